// Round 1
// baseline (1564.900 us; speedup 1.0000x reference)
//
#include <hip/hip_runtime.h>
#include <math.h>

#define B_ 64
#define T_ 30
#define NROW 1920      // B*T
#define HID_ 256
#define SENC 100
#define VOCAB_ 50000

// ---------------------------------------------------------------------------
// Embedding gather: emb[n][e] = wemb[comment_input[n]][e]
// ---------------------------------------------------------------------------
__global__ void gather_emb_kernel(const int* __restrict__ tokens,
                                  const float* __restrict__ wemb,
                                  float* __restrict__ emb) {
    int n = blockIdx.x;
    int e = threadIdx.x;
    int tok = tokens[n];
    emb[(size_t)n * 256 + e] = wemb[(size_t)tok * 256 + e];
}

// ---------------------------------------------------------------------------
// Generic fp32 GEMM: C[m][n] = act(sum_k A[m][k]*B[n][k] + bias[n])
// A: M x K row-major, B: N x K row-major (i.e. C = A @ B^T + bias)
// M must be a multiple of 64 (true for all call sites: 64, 1920).
// Tiles: BM=64, BN=64, BK=32; 256 threads; 4x4 per-thread micro-tile.
// ---------------------------------------------------------------------------
template <bool RELU>
__global__ __launch_bounds__(256) void gemm_nt_kernel(
    const float* __restrict__ A, const float* __restrict__ Bm,
    const float* __restrict__ bias, float* __restrict__ C,
    int M, int N, int K) {
    __shared__ float As[32][68];   // [k][m], padded to 68 to break conflicts
    __shared__ float Bs[32][68];   // [k][n]

    const int tid = threadIdx.x;
    const int m0 = blockIdx.y * 64;
    const int n0 = blockIdx.x * 64;

    const int tx = tid & 15;       // n direction
    const int ty = tid >> 4;       // m direction

    const int lrow = tid >> 3;         // 0..31
    const int lcol = (tid & 7) * 4;    // 0,4,...,28

    float acc[4][4];
#pragma unroll
    for (int i = 0; i < 4; ++i)
#pragma unroll
        for (int j = 0; j < 4; ++j) acc[i][j] = 0.f;

    for (int k0 = 0; k0 < K; k0 += 32) {
#pragma unroll
        for (int half = 0; half < 2; ++half) {
            int m = lrow + half * 32;
            float4 av = *reinterpret_cast<const float4*>(
                A + (size_t)(m0 + m) * K + k0 + lcol);
            As[lcol + 0][m] = av.x;
            As[lcol + 1][m] = av.y;
            As[lcol + 2][m] = av.z;
            As[lcol + 3][m] = av.w;

            int n = lrow + half * 32;
            float4 bv = make_float4(0.f, 0.f, 0.f, 0.f);
            if (n0 + n < N) {
                bv = *reinterpret_cast<const float4*>(
                    Bm + (size_t)(n0 + n) * K + k0 + lcol);
            }
            Bs[lcol + 0][n] = bv.x;
            Bs[lcol + 1][n] = bv.y;
            Bs[lcol + 2][n] = bv.z;
            Bs[lcol + 3][n] = bv.w;
        }
        __syncthreads();

#pragma unroll
        for (int k = 0; k < 32; ++k) {
            float4 a4 = *reinterpret_cast<const float4*>(&As[k][ty * 4]);
            float4 b4 = *reinterpret_cast<const float4*>(&Bs[k][tx * 4]);
            float a[4] = {a4.x, a4.y, a4.z, a4.w};
            float b[4] = {b4.x, b4.y, b4.z, b4.w};
#pragma unroll
            for (int i = 0; i < 4; ++i)
#pragma unroll
                for (int j = 0; j < 4; ++j) acc[i][j] = fmaf(a[i], b[j], acc[i][j]);
        }
        __syncthreads();
    }

#pragma unroll
    for (int i = 0; i < 4; ++i) {
        int m = m0 + ty * 4 + i;
#pragma unroll
        for (int j = 0; j < 4; ++j) {
            int n = n0 + tx * 4 + j;
            if (n < N) {
                float v = acc[i][j] + bias[n];
                if (RELU) v = fmaxf(v, 0.f);
                C[(size_t)m * N + n] = v;
            }
        }
    }
}

// ---------------------------------------------------------------------------
// GRU cell (non-recurrent: gh broadcast over t). Writes dec into cat[:,256:512].
// ---------------------------------------------------------------------------
__global__ void dec_kernel(const float* __restrict__ gi,
                           const float* __restrict__ gh,
                           const float* __restrict__ h0,
                           float* __restrict__ cat) {
    int n = blockIdx.x;   // 0..1919
    int h = threadIdx.x;  // 0..255
    int b = n / 30;
    float gir = gi[(size_t)n * 768 + h];
    float giz = gi[(size_t)n * 768 + 256 + h];
    float gin = gi[(size_t)n * 768 + 512 + h];
    float ghr = gh[(size_t)b * 768 + h];
    float ghz = gh[(size_t)b * 768 + 256 + h];
    float ghn = gh[(size_t)b * 768 + 512 + h];
    float r = 1.f / (1.f + expf(-(gir + ghr)));
    float z = 1.f / (1.f + expf(-(giz + ghz)));
    float nn = tanhf(gin + r * ghn);
    float h0v = h0[(size_t)b * 256 + h];
    cat[(size_t)n * 768 + 256 + h] = (1.f - z) * nn + z * h0v;
}

// ---------------------------------------------------------------------------
// Attention for one encoder. NOTE: keys come from a *reshape* of enc:
//   keys[b][h][s] = enc_flat[b*25600 + h*100 + s]
// while ctx uses the original layout enc[b][s][h].
// One block per (b,t) row. Writes ctx into cat[:, colbase:colbase+256].
// ---------------------------------------------------------------------------
__global__ __launch_bounds__(256) void attn_kernel(
    const float* __restrict__ enc, float* __restrict__ cat, int colbase) {
    __shared__ float decs[256];
    __shared__ float sc[100];
    __shared__ float red[2];

    int n = blockIdx.x;
    int b = n / 30;
    int tid = threadIdx.x;

    decs[tid] = cat[(size_t)n * 768 + 256 + tid];
    __syncthreads();

    const float* e = enc + (size_t)b * 25600;

    if (tid < 100) {
        float acc = 0.f;
        for (int h = 0; h < 256; ++h) acc = fmaf(decs[h], e[h * 100 + tid], acc);
        sc[tid] = acc;
    }
    __syncthreads();
    if (tid == 0) {
        float mx = sc[0];
        for (int s = 1; s < 100; ++s) mx = fmaxf(mx, sc[s]);
        red[0] = mx;
    }
    __syncthreads();
    if (tid < 100) sc[tid] = expf(sc[tid] - red[0]);
    __syncthreads();
    if (tid == 0) {
        float sum = 0.f;
        for (int s = 0; s < 100; ++s) sum += sc[s];
        red[1] = 1.f / sum;
    }
    __syncthreads();

    float inv = red[1];
    float acc = 0.f;
    for (int s = 0; s < 100; ++s) acc = fmaf(sc[s], e[s * 256 + tid], acc);
    cat[(size_t)n * 768 + colbase + tid] = acc * inv;
}

// ---------------------------------------------------------------------------
// Per-row log_softmax (in place) + argmax (first occurrence) written as float.
// One block per row; 3 strided passes (row = 200KB, passes 2-3 are L2-hot).
// ---------------------------------------------------------------------------
__global__ __launch_bounds__(256) void lse_kernel(float* __restrict__ logits,
                                                  float* __restrict__ seq) {
    __shared__ float rv[256];
    __shared__ int ri[256];
    __shared__ float rs[256];

    int row = blockIdx.x;
    int tid = threadIdx.x;
    float* p = logits + (size_t)row * VOCAB_;

    float mv = -3.402823466e38f;
    int mi = 0;
    for (int i = tid; i < VOCAB_; i += 256) {
        float v = p[i];
        if (v > mv) { mv = v; mi = i; }   // strict > keeps first occurrence
    }
    rv[tid] = mv;
    ri[tid] = mi;
    __syncthreads();
    for (int off = 128; off > 0; off >>= 1) {
        if (tid < off) {
            float ov = rv[tid + off];
            int oi = ri[tid + off];
            if (ov > rv[tid] || (ov == rv[tid] && oi < ri[tid])) {
                rv[tid] = ov;
                ri[tid] = oi;
            }
        }
        __syncthreads();
    }
    float gmax = rv[0];

    float s = 0.f;
    for (int i = tid; i < VOCAB_; i += 256) s += expf(p[i] - gmax);
    rs[tid] = s;
    __syncthreads();
    for (int off = 128; off > 0; off >>= 1) {
        if (tid < off) rs[tid] += rs[tid + off];
        __syncthreads();
    }
    float lse = gmax + logf(rs[0]);

    for (int i = tid; i < VOCAB_; i += 256) p[i] = p[i] - lse;
    if (tid == 0) seq[row] = (float)ri[0];
}

// ---------------------------------------------------------------------------
extern "C" void kernel_launch(void* const* d_in, const int* in_sizes, int n_in,
                              void* d_out, int out_size, void* d_ws, size_t ws_size,
                              hipStream_t stream) {
    const int* comment_input = (const int*)d_in[1];   // (64,30)
    const float* tok_output  = (const float*)d_in[2]; // (64,100,256)
    const float* h0          = (const float*)d_in[3]; // (1,64,256)
    const float* sbtao       = (const float*)d_in[4]; // (64,100,256)
    const float* wemb        = (const float*)d_in[5]; // (50000,256)
    const float* W_ih        = (const float*)d_in[6]; // (768,256)
    const float* W_hh        = (const float*)d_in[7]; // (768,256)
    const float* b_ih        = (const float*)d_in[8];
    const float* b_hh        = (const float*)d_in[9];
    const float* W1          = (const float*)d_in[10]; // (256,768)
    const float* b1          = (const float*)d_in[11];
    const float* W2          = (const float*)d_in[12]; // (50000,256)
    const float* b2          = (const float*)d_in[13];

    float* out    = (float*)d_out;
    float* seq    = out;            // 1920 floats (argmax indices as floats)
    float* logits = out + NROW;     // 1920 x 50000

    float* ws   = (float*)d_ws;
    float* emb  = ws;               // 1920*256  = 491520
    float* gi   = emb + 491520;     // 1920*768  = 1474560
    float* gh   = gi + 1474560;     // 64*768    = 49152
    float* cat  = gh + 49152;       // 1920*768  = 1474560
    float* out1 = cat + 1474560;    // 1920*256  = 491520

    gather_emb_kernel<<<NROW, 256, 0, stream>>>(comment_input, wemb, emb);

    // gh = h0 @ W_hh^T + b_hh   (64 x 768, K=256)
    gemm_nt_kernel<false><<<dim3(12, 1), 256, 0, stream>>>(
        h0, W_hh, b_hh, gh, 64, 768, 256);

    // gi = emb @ W_ih^T + b_ih  (1920 x 768, K=256)
    gemm_nt_kernel<false><<<dim3(12, 30), 256, 0, stream>>>(
        emb, W_ih, b_ih, gi, NROW, 768, 256);

    // dec -> cat[:,256:512]
    dec_kernel<<<NROW, 256, 0, stream>>>(gi, gh, h0, cat);

    // ctx -> cat[:,0:256], ast_ctx -> cat[:,512:768]
    attn_kernel<<<NROW, 256, 0, stream>>>(tok_output, cat, 0);
    attn_kernel<<<NROW, 256, 0, stream>>>(sbtao, cat, 512);

    // out1 = relu(cat @ W1^T + b1)  (1920 x 256, K=768)
    gemm_nt_kernel<true><<<dim3(4, 30), 256, 0, stream>>>(
        cat, W1, b1, out1, NROW, 256, 768);

    // logits = relu(out1 @ W2^T + b2)  (1920 x 50000, K=256)
    gemm_nt_kernel<true><<<dim3(782, 30), 256, 0, stream>>>(
        out1, W2, b2, logits, NROW, VOCAB_, 256);

    // log_softmax in place + argmax
    lse_kernel<<<NROW, 256, 0, stream>>>(logits, seq);
}

// Round 2
// 975.717 us; speedup vs baseline: 1.6038x; 1.6038x over previous
//
#include <hip/hip_runtime.h>
#include <hip/hip_bf16.h>
#include <math.h>

#define NROW 1920      // B*T
#define VOCAB_ 50000
#define NPAD 50048     // 391 * 128
#define NBLK 391
#define LDBF 72        // padded LDS stride (bf16 elems): 144B = 36 banks -> 2-way max (free)

typedef __attribute__((ext_vector_type(8))) short short8;
typedef __attribute__((ext_vector_type(4))) float floatx4;

__device__ inline ushort f32_to_bf16_bits(float f) {
    union { float f; unsigned u; } v; v.f = f;
    unsigned u = v.u;
    u += 0x7fffu + ((u >> 16) & 1u);   // RNE
    return (ushort)(u >> 16);
}

// ---------------------------------------------------------------------------
__global__ void gather_emb_kernel(const int* __restrict__ tokens,
                                  const float* __restrict__ wemb,
                                  float* __restrict__ emb) {
    int n = blockIdx.x;
    int e = threadIdx.x;
    int tok = tokens[n];
    emb[(size_t)n * 256 + e] = wemb[(size_t)tok * 256 + e];
}

// ---------------------------------------------------------------------------
// fp32 vector GEMM for the small matmuls: C = act(A @ B^T + bias)
// ---------------------------------------------------------------------------
template <bool RELU>
__global__ __launch_bounds__(256) void gemm_nt_kernel(
    const float* __restrict__ A, const float* __restrict__ Bm,
    const float* __restrict__ bias, float* __restrict__ C,
    int M, int N, int K) {
    __shared__ float As[32][68];
    __shared__ float Bs[32][68];

    const int tid = threadIdx.x;
    const int m0 = blockIdx.y * 64;
    const int n0 = blockIdx.x * 64;
    const int tx = tid & 15;
    const int ty = tid >> 4;
    const int lrow = tid >> 3;
    const int lcol = (tid & 7) * 4;

    float acc[4][4];
#pragma unroll
    for (int i = 0; i < 4; ++i)
#pragma unroll
        for (int j = 0; j < 4; ++j) acc[i][j] = 0.f;

    for (int k0 = 0; k0 < K; k0 += 32) {
#pragma unroll
        for (int half = 0; half < 2; ++half) {
            int m = lrow + half * 32;
            float4 av = *reinterpret_cast<const float4*>(
                A + (size_t)(m0 + m) * K + k0 + lcol);
            As[lcol + 0][m] = av.x; As[lcol + 1][m] = av.y;
            As[lcol + 2][m] = av.z; As[lcol + 3][m] = av.w;
            int n = lrow + half * 32;
            float4 bv = make_float4(0.f, 0.f, 0.f, 0.f);
            if (n0 + n < N)
                bv = *reinterpret_cast<const float4*>(
                    Bm + (size_t)(n0 + n) * K + k0 + lcol);
            Bs[lcol + 0][n] = bv.x; Bs[lcol + 1][n] = bv.y;
            Bs[lcol + 2][n] = bv.z; Bs[lcol + 3][n] = bv.w;
        }
        __syncthreads();
#pragma unroll
        for (int k = 0; k < 32; ++k) {
            float4 a4 = *reinterpret_cast<const float4*>(&As[k][ty * 4]);
            float4 b4 = *reinterpret_cast<const float4*>(&Bs[k][tx * 4]);
            float a[4] = {a4.x, a4.y, a4.z, a4.w};
            float b[4] = {b4.x, b4.y, b4.z, b4.w};
#pragma unroll
            for (int i = 0; i < 4; ++i)
#pragma unroll
                for (int j = 0; j < 4; ++j) acc[i][j] = fmaf(a[i], b[j], acc[i][j]);
        }
        __syncthreads();
    }
#pragma unroll
    for (int i = 0; i < 4; ++i) {
        int m = m0 + ty * 4 + i;
#pragma unroll
        for (int j = 0; j < 4; ++j) {
            int n = n0 + tx * 4 + j;
            if (n < N) {
                float v = acc[i][j] + bias[n];
                if (RELU) v = fmaxf(v, 0.f);
                C[(size_t)m * N + n] = v;
            }
        }
    }
}

// ---------------------------------------------------------------------------
__global__ void dec_kernel(const float* __restrict__ gi,
                           const float* __restrict__ gh,
                           const float* __restrict__ h0,
                           float* __restrict__ cat) {
    int n = blockIdx.x;
    int h = threadIdx.x;
    int b = n / 30;
    float gir = gi[(size_t)n * 768 + h];
    float giz = gi[(size_t)n * 768 + 256 + h];
    float gin = gi[(size_t)n * 768 + 512 + h];
    float ghr = gh[(size_t)b * 768 + h];
    float ghz = gh[(size_t)b * 768 + 256 + h];
    float ghn = gh[(size_t)b * 768 + 512 + h];
    float r = 1.f / (1.f + expf(-(gir + ghr)));
    float z = 1.f / (1.f + expf(-(giz + ghz)));
    float nn = tanhf(gin + r * ghn);
    float h0v = h0[(size_t)b * 256 + h];
    cat[(size_t)n * 768 + 256 + h] = (1.f - z) * nn + z * h0v;
}

// ---------------------------------------------------------------------------
// keys[b][h][s] = enc_flat[b*25600 + h*100 + s]  (reshape, NOT transpose)
// ---------------------------------------------------------------------------
__global__ __launch_bounds__(256) void attn_kernel(
    const float* __restrict__ enc, float* __restrict__ cat, int colbase) {
    __shared__ float decs[256];
    __shared__ float sc[100];
    __shared__ float red[2];

    int n = blockIdx.x;
    int b = n / 30;
    int tid = threadIdx.x;

    decs[tid] = cat[(size_t)n * 768 + 256 + tid];
    __syncthreads();
    const float* e = enc + (size_t)b * 25600;
    if (tid < 100) {
        float acc = 0.f;
        for (int h = 0; h < 256; ++h) acc = fmaf(decs[h], e[h * 100 + tid], acc);
        sc[tid] = acc;
    }
    __syncthreads();
    if (tid == 0) {
        float mx = sc[0];
        for (int s = 1; s < 100; ++s) mx = fmaxf(mx, sc[s]);
        red[0] = mx;
    }
    __syncthreads();
    if (tid < 100) sc[tid] = expf(sc[tid] - red[0]);
    __syncthreads();
    if (tid == 0) {
        float sum = 0.f;
        for (int s = 0; s < 100; ++s) sum += sc[s];
        red[1] = 1.f / sum;
    }
    __syncthreads();
    float inv = red[1];
    float acc = 0.f;
    for (int s = 0; s < 100; ++s) acc = fmaf(sc[s], e[s * 256 + tid], acc);
    cat[(size_t)n * 768 + colbase + tid] = acc * inv;
}

// ---------------------------------------------------------------------------
// fp32 -> bf16 converters
// ---------------------------------------------------------------------------
__global__ void conv_out1_kernel(const float* __restrict__ src, ushort* __restrict__ dst) {
    size_t i = (size_t)blockIdx.x * 256 + threadIdx.x;
    dst[i] = f32_to_bf16_bits(src[i]);
}

__global__ void conv_w2_kernel(const float* __restrict__ W2, ushort* __restrict__ Wb) {
    int row = blockIdx.x;
    int col = threadIdx.x;
    float v = (row < VOCAB_) ? W2[(size_t)row * 256 + col] : 0.f;
    Wb[(size_t)row * 256 + col] = f32_to_bf16_bits(v);
}

// ---------------------------------------------------------------------------
// bf16 MFMA GEMM: logits = relu(A_bf16 @ B_bf16^T + b2), fp32 out.
// 128x128 tile, BK=64, 4 waves each 64x64 (4x4 of 16x16x32 MFMA).
// Epilogue: per-row partial max + sum(exp(v-max)) over this block's 128 cols
// -> pmax/psum[row][nblk].  grid = (15 m-tiles, 391 n-tiles), m fastest so
// the 1MB bf16 A stays L2-resident and concurrent blocks share B tiles.
// ---------------------------------------------------------------------------
__global__ __launch_bounds__(256) void mfma_gemm_kernel(
    const ushort* __restrict__ Abf, const ushort* __restrict__ Bbf,
    const float* __restrict__ b2, float* __restrict__ C,
    float* __restrict__ pmax, float* __restrict__ psum) {
    __shared__ ushort As[128 * LDBF];
    __shared__ ushort Bs[128 * LDBF];
    __shared__ float pmL[128][2];
    __shared__ float psL[128][2];

    const int tid = threadIdx.x;
    const int m0 = blockIdx.x * 128;
    const int n0 = blockIdx.y * 128;
    const int nblk = blockIdx.y;
    const int wave = tid >> 6, lane = tid & 63;
    const int wm = wave >> 1, wn = wave & 1;
    const int q = lane >> 4, ln = lane & 15;

    const int srow = tid >> 1;
    const int sseg = (tid & 1) * 32;

    floatx4 acc[4][4];
#pragma unroll
    for (int i = 0; i < 4; ++i)
#pragma unroll
        for (int j = 0; j < 4; ++j) acc[i][j] = (floatx4)0.f;

    for (int k0 = 0; k0 < 256; k0 += 64) {
        const uint4* asrc = reinterpret_cast<const uint4*>(
            Abf + (size_t)(m0 + srow) * 256 + k0 + sseg);
        uint4 a0 = asrc[0], a1 = asrc[1], a2 = asrc[2], a3 = asrc[3];
        const uint4* bsrc = reinterpret_cast<const uint4*>(
            Bbf + (size_t)(n0 + srow) * 256 + k0 + sseg);
        uint4 c0 = bsrc[0], c1 = bsrc[1], c2 = bsrc[2], c3 = bsrc[3];
        __syncthreads();
        uint4* ad = reinterpret_cast<uint4*>(&As[srow * LDBF + sseg]);
        ad[0] = a0; ad[1] = a1; ad[2] = a2; ad[3] = a3;
        uint4* bd = reinterpret_cast<uint4*>(&Bs[srow * LDBF + sseg]);
        bd[0] = c0; bd[1] = c1; bd[2] = c2; bd[3] = c3;
        __syncthreads();
#pragma unroll
        for (int ks = 0; ks < 2; ++ks) {
            short8 af[4], bf[4];
#pragma unroll
            for (int mt = 0; mt < 4; ++mt)
                af[mt] = *reinterpret_cast<const short8*>(
                    &As[(wm * 64 + mt * 16 + ln) * LDBF + ks * 32 + q * 8]);
#pragma unroll
            for (int nt = 0; nt < 4; ++nt)
                bf[nt] = *reinterpret_cast<const short8*>(
                    &Bs[(wn * 64 + nt * 16 + ln) * LDBF + ks * 32 + q * 8]);
#pragma unroll
            for (int mt = 0; mt < 4; ++mt)
#pragma unroll
                for (int nt = 0; nt < 4; ++nt)
                    acc[mt][nt] = __builtin_amdgcn_mfma_f32_16x16x32_bf16(
                        af[mt], bf[nt], acc[mt][nt], 0, 0, 0);
        }
    }

    // epilogue: bias + relu + store + per-row partial softmax stats
    float bias[4]; int nn[4];
#pragma unroll
    for (int nt = 0; nt < 4; ++nt) {
        int n = n0 + wn * 64 + nt * 16 + ln;
        nn[nt] = n;
        bias[nt] = (n < VOCAB_) ? b2[n] : 0.f;
    }
#pragma unroll
    for (int mt = 0; mt < 4; ++mt) {
#pragma unroll
        for (int r = 0; r < 4; ++r) {
            int m = m0 + wm * 64 + mt * 16 + q * 4 + r;
            float vv[4]; float lmax = -1e30f;
#pragma unroll
            for (int nt = 0; nt < 4; ++nt) {
                float v = acc[mt][nt][r] + bias[nt];
                v = fmaxf(v, 0.f);
                if (nn[nt] < VOCAB_) C[(size_t)m * VOCAB_ + nn[nt]] = v;
                else v = -1e30f;
                vv[nt] = v;
                lmax = fmaxf(lmax, v);
            }
#pragma unroll
            for (int off = 1; off < 16; off <<= 1)
                lmax = fmaxf(lmax, __shfl_xor(lmax, off, 64));
            float ls = 0.f;
#pragma unroll
            for (int nt = 0; nt < 4; ++nt) ls += __expf(vv[nt] - lmax);
#pragma unroll
            for (int off = 1; off < 16; off <<= 1)
                ls += __shfl_xor(ls, off, 64);
            if (ln == 0) {
                int rl = wm * 64 + mt * 16 + q * 4 + r;
                pmL[rl][wn] = lmax;
                psL[rl][wn] = ls;
            }
        }
    }
    __syncthreads();
    if (tid < 128) {
        float m1 = pmL[tid][0], m2 = pmL[tid][1];
        float nm = fmaxf(m1, m2);
        float s = psL[tid][0] * __expf(m1 - nm) + psL[tid][1] * __expf(m2 - nm);
        pmax[(size_t)(m0 + tid) * NBLK + nblk] = nm;
        psum[(size_t)(m0 + tid) * NBLK + nblk] = s;
    }
}

// ---------------------------------------------------------------------------
// Merge 391 per-block partials per row -> row_max, row_lse
// ---------------------------------------------------------------------------
__global__ __launch_bounds__(128) void reduce_rows_kernel(
    const float* __restrict__ pmax, const float* __restrict__ psum,
    float* __restrict__ row_max, float* __restrict__ row_lse) {
    __shared__ float sm[128], ss[128];
    int row = blockIdx.x, tid = threadIdx.x;
    const float* pm = pmax + (size_t)row * NBLK;
    const float* ps = psum + (size_t)row * NBLK;
    float m = -1e30f, s = 0.f;
    for (int i = tid; i < NBLK; i += 128) {
        float m2 = pm[i], s2 = ps[i];
        float nm = fmaxf(m, m2);
        s = s * __expf(m - nm) + s2 * __expf(m2 - nm);
        m = nm;
    }
    sm[tid] = m; ss[tid] = s;
    __syncthreads();
    for (int off = 64; off > 0; off >>= 1) {
        if (tid < off) {
            float m2 = sm[tid + off], s2 = ss[tid + off];
            float nm = fmaxf(sm[tid], m2);
            ss[tid] = ss[tid] * __expf(sm[tid] - nm) + s2 * __expf(m2 - nm);
            sm[tid] = nm;
        }
        __syncthreads();
    }
    if (tid == 0) {
        row_max[row] = sm[0];
        row_lse[row] = sm[0] + logf(ss[0]);
    }
}

// ---------------------------------------------------------------------------
// Per row: logprob = logit - lse (in place), collect candidates within margin
// of max, recompute candidates exactly in fp64, write exact argmax as float.
// ---------------------------------------------------------------------------
__global__ __launch_bounds__(256) void final_kernel(
    float* __restrict__ logits, const float* __restrict__ row_max,
    const float* __restrict__ row_lse, const float* __restrict__ out1,
    const float* __restrict__ W2, const float* __restrict__ b2,
    float* __restrict__ seq) {
    __shared__ float o1s[256];
    __shared__ int cnt;
    __shared__ int cand[128];
    __shared__ double red[256];
    __shared__ double bestv_s;
    __shared__ int besti_s;

    int row = blockIdx.x, tid = threadIdx.x;
    if (tid == 0) { cnt = 0; bestv_s = -1e300; besti_s = 0x7fffffff; }
    o1s[tid] = out1[(size_t)row * 256 + tid];
    __syncthreads();

    float rmax = row_max[row], rlse = row_lse[row];
    float thr = rmax - 0.03f;
    float* p = logits + (size_t)row * VOCAB_;
    float4* p4 = reinterpret_cast<float4*>(p);
    for (int i = tid; i < VOCAB_ / 4; i += 256) {
        float4 v = p4[i];
        if (v.x >= thr) { int k = atomicAdd(&cnt, 1); if (k < 128) cand[k] = i * 4; }
        if (v.y >= thr) { int k = atomicAdd(&cnt, 1); if (k < 128) cand[k] = i * 4 + 1; }
        if (v.z >= thr) { int k = atomicAdd(&cnt, 1); if (k < 128) cand[k] = i * 4 + 2; }
        if (v.w >= thr) { int k = atomicAdd(&cnt, 1); if (k < 128) cand[k] = i * 4 + 3; }
        v.x -= rlse; v.y -= rlse; v.z -= rlse; v.w -= rlse;
        p4[i] = v;
    }
    __syncthreads();
    int nc = min(cnt, 128);
    for (int j = 0; j < nc; ++j) {
        int c = cand[j];
        red[tid] = (double)o1s[tid] * (double)W2[(size_t)c * 256 + tid];
        __syncthreads();
        for (int off = 128; off > 0; off >>= 1) {
            if (tid < off) red[tid] += red[tid + off];
            __syncthreads();
        }
        if (tid == 0) {
            double v = red[0] + (double)b2[c];
            if (v < 0.0) v = 0.0;
            if (v > bestv_s || (v == bestv_s && c < besti_s)) { bestv_s = v; besti_s = c; }
        }
        __syncthreads();
    }
    if (tid == 0) seq[row] = (float)besti_s;
}

// ---------------------------------------------------------------------------
extern "C" void kernel_launch(void* const* d_in, const int* in_sizes, int n_in,
                              void* d_out, int out_size, void* d_ws, size_t ws_size,
                              hipStream_t stream) {
    const int* comment_input = (const int*)d_in[1];
    const float* tok_output  = (const float*)d_in[2];
    const float* h0          = (const float*)d_in[3];
    const float* sbtao       = (const float*)d_in[4];
    const float* wemb        = (const float*)d_in[5];
    const float* W_ih        = (const float*)d_in[6];
    const float* W_hh        = (const float*)d_in[7];
    const float* b_ih        = (const float*)d_in[8];
    const float* b_hh        = (const float*)d_in[9];
    const float* W1          = (const float*)d_in[10];
    const float* b1          = (const float*)d_in[11];
    const float* W2          = (const float*)d_in[12];
    const float* b2          = (const float*)d_in[13];

    float* out    = (float*)d_out;
    float* seq    = out;
    float* logits = out + NROW;

    float* ws      = (float*)d_ws;
    float* emb     = ws;                    // 491520
    float* gi      = emb + 491520;          // 1474560
    float* gh      = gi + 1474560;          // 49152
    float* cat     = gh + 49152;            // 1474560
    float* out1    = cat + 1474560;         // 491520
    float* pmax    = out1 + 491520;         // 1920*391 = 750720
    float* psum    = pmax + 750720;         // 750720
    float* row_max = psum + 750720;         // 1920
    float* row_lse = row_max + 1920;        // 1920
    ushort* out1b  = (ushort*)(row_lse + 1920);       // 1920*256 bf16
    ushort* W2b    = (ushort*)(row_lse + 1920 + 245760); // 50048*256 bf16

    gather_emb_kernel<<<NROW, 256, 0, stream>>>(comment_input, wemb, emb);

    gemm_nt_kernel<false><<<dim3(12, 1), 256, 0, stream>>>(
        h0, W_hh, b_hh, gh, 64, 768, 256);
    gemm_nt_kernel<false><<<dim3(12, 30), 256, 0, stream>>>(
        emb, W_ih, b_ih, gi, NROW, 768, 256);
    dec_kernel<<<NROW, 256, 0, stream>>>(gi, gh, h0, cat);
    attn_kernel<<<NROW, 256, 0, stream>>>(tok_output, cat, 0);
    attn_kernel<<<NROW, 256, 0, stream>>>(sbtao, cat, 512);
    gemm_nt_kernel<true><<<dim3(4, 30), 256, 0, stream>>>(
        cat, W1, b1, out1, NROW, 256, 768);

    conv_out1_kernel<<<NROW, 256, 0, stream>>>(out1, out1b);
    conv_w2_kernel<<<NPAD, 256, 0, stream>>>(W2, W2b);

    mfma_gemm_kernel<<<dim3(15, NBLK), 256, 0, stream>>>(
        out1b, W2b, b2, logits, pmax, psum);

    reduce_rows_kernel<<<NROW, 128, 0, stream>>>(pmax, psum, row_max, row_lse);

    final_kernel<<<NROW, 256, 0, stream>>>(
        logits, row_max, row_lse, out1, W2, b2, seq);
}